// Round 6
// baseline (416.565 us; speedup 1.0000x reference)
//
#include <hip/hip_runtime.h>
#include <math.h>

#define D_MODEL 1024
#define NUM_EXPERTS 8
#define TOPK 2
#define TM 128
#define TN 128
#define BK 32
#define NSTEP 96                          // 3 planes x 32 K-steps
#define MAXT (16384 / TM + NUM_EXPERTS)   // 136 padded tiles

typedef __attribute__((ext_vector_type(8))) short short8;
typedef __attribute__((ext_vector_type(4))) float f32x4;
typedef unsigned short ushort_t;

__device__ __forceinline__ unsigned short bf16_rne(float f) {
    unsigned int u = __builtin_bit_cast(unsigned int, f);
    unsigned int r = u + 0x7fffu + ((u >> 16) & 1u);
    return (unsigned short)(r >> 16);
}
__device__ __forceinline__ float bf16f(unsigned short h) {
    unsigned int u = ((unsigned int)h) << 16;
    return __builtin_bit_cast(float, u);
}
__device__ __forceinline__ void gload_lds16(const ushort_t* g, ushort_t* l) {
    __builtin_amdgcn_global_load_lds(
        (const __attribute__((address_space(1))) unsigned int*)g,
        (__attribute__((address_space(3))) unsigned int*)l, 16, 0, 0);
}
__device__ __forceinline__ void split2(float v, unsigned short& h, unsigned short& l) {
    h = bf16_rne(v); l = bf16_rne(v - bf16f(h));
}

// ---- convert We -> packed staging order [e][ct][ks][kg][col][8], hi/lo planes ----
// thread reads 16 consecutive k of one (e,ct,col) row: coalesced reads,
// 2x 16B writes per plane (sibling cols merge 64B lines in L2)
__global__ __launch_bounds__(256) void convert_W_pack(
    const float* __restrict__ W, ushort_t* __restrict__ hi, ushort_t* __restrict__ lo)
{
    int t = blockIdx.x * 256 + threadIdx.x;          // 524288 threads
    int k16 = t & 63, col = (t >> 6) & 127, ct = (t >> 13) & 7, e = t >> 16;
    int ks = k16 >> 1, kg0 = (k16 & 1) * 2;
    const float4* src = (const float4*)(W + ((size_t)(e * 1024 + ct * 128 + col)) * 1024
                                          + k16 * 16);
    float4 v0 = src[0], v1 = src[1], v2 = src[2], v3 = src[3];
    size_t base = (size_t)(e * 8 + ct) * 131072 + (size_t)ks * 4096;
    size_t o0 = base + (size_t)(kg0 * 128 + col) * 8;
    size_t o1 = base + (size_t)((kg0 + 1) * 128 + col) * 8;
    ushort4 h, l;
    split2(v0.x, h.x, l.x); split2(v0.y, h.y, l.y); split2(v0.z, h.z, l.z); split2(v0.w, h.w, l.w);
    ((ushort4*)(hi + o0))[0] = h; ((ushort4*)(lo + o0))[0] = l;
    split2(v1.x, h.x, l.x); split2(v1.y, h.y, l.y); split2(v1.z, h.z, l.z); split2(v1.w, h.w, l.w);
    ((ushort4*)(hi + o0))[1] = h; ((ushort4*)(lo + o0))[1] = l;
    split2(v2.x, h.x, l.x); split2(v2.y, h.y, l.y); split2(v2.z, h.z, l.z); split2(v2.w, h.w, l.w);
    ((ushort4*)(hi + o1))[0] = h; ((ushort4*)(lo + o1))[0] = l;
    split2(v3.x, h.x, l.x); split2(v3.y, h.y, l.y); split2(v3.z, h.z, l.z); split2(v3.w, h.w, l.w);
    ((ushort4*)(hi + o1))[1] = h; ((ushort4*)(lo + o1))[1] = l;
}

// ---- fused gating + x -> hi/lo bf16 planes (x read once), one wave per token ----
__global__ __launch_bounds__(256) void gate_cvt_x(
    const float* __restrict__ x, const float* __restrict__ Wg,
    const float* __restrict__ bg,
    ushort_t* __restrict__ xhi, ushort_t* __restrict__ xlo,
    int* __restrict__ eidx, float* __restrict__ ew, int N)
{
    const int wave = threadIdx.x >> 6, lane = threadIdx.x & 63;
    const int n = blockIdx.x * 4 + wave;
    if (n >= N) return;

    const float4* xr4 = (const float4*)(x + (size_t)n * D_MODEL);
    float xv[16];
#pragma unroll
    for (int j = 0; j < 4; ++j) {
        float4 v = xr4[j * 64 + lane];
        xv[4 * j + 0] = v.x; xv[4 * j + 1] = v.y;
        xv[4 * j + 2] = v.z; xv[4 * j + 3] = v.w;
        ushort4 h, l;
        split2(v.x, h.x, l.x); split2(v.y, h.y, l.y);
        split2(v.z, h.z, l.z); split2(v.w, h.w, l.w);
        ((ushort4*)(xhi + (size_t)n * D_MODEL))[j * 64 + lane] = h;
        ((ushort4*)(xlo + (size_t)n * D_MODEL))[j * 64 + lane] = l;
    }
    float logit[NUM_EXPERTS];
#pragma unroll
    for (int e = 0; e < NUM_EXPERTS; ++e) {
        const float4* wg4 = (const float4*)(Wg + (size_t)e * D_MODEL);
        float p = 0.f;
#pragma unroll
        for (int j = 0; j < 4; ++j) {
            float4 w = wg4[j * 64 + lane];
            p += xv[4 * j + 0] * w.x + xv[4 * j + 1] * w.y
               + xv[4 * j + 2] * w.z + xv[4 * j + 3] * w.w;
        }
#pragma unroll
        for (int off = 32; off >= 1; off >>= 1) p += __shfl_xor(p, off, 64);
        logit[e] = p + bg[e];
    }
    int i0 = 0; float v0 = logit[0];
#pragma unroll
    for (int e = 1; e < NUM_EXPERTS; ++e)
        if (logit[e] > v0) { v0 = logit[e]; i0 = e; }
    int i1 = -1; float v1 = -INFINITY;
#pragma unroll
    for (int e = 0; e < NUM_EXPERTS; ++e) {
        if (e == i0) continue;
        if (logit[e] > v1) { v1 = logit[e]; i1 = e; }
    }
    float e1 = expf(v1 - v0);
    float inv = 1.f / (1.f + e1);
    if (lane == 0) {
        eidx[2 * n]     = i0;
        eidx[2 * n + 1] = i1;
        ew[2 * n]       = inv;
        ew[2 * n + 1]   = e1 * inv;
    }
}

// ---- histogram: block-aggregated, 8 atomics per block ----
__global__ __launch_bounds__(256) void moe_count(
    const int* __restrict__ eidx, int* __restrict__ counts)
{
    __shared__ int h[NUM_EXPERTS];
    if (threadIdx.x < NUM_EXPERTS) h[threadIdx.x] = 0;
    __syncthreads();
    int e = eidx[blockIdx.x * 256 + threadIdx.x];
    atomicAdd(&h[e], 1);
    __syncthreads();
    if (threadIdx.x < NUM_EXPERTS) atomicAdd(&counts[threadIdx.x], h[threadIdx.x]);
}

// ---- scan ----
__global__ void moe_scan(const int* __restrict__ counts,
                         int* __restrict__ tileBase, int* __restrict__ cursorP,
                         int* __restrict__ totalTiles)
{
    int tb = 0;
    for (int e = 0; e < NUM_EXPERTS; ++e) {
        tileBase[e] = tb;
        cursorP[e]  = tb * TM;
        tb += (counts[e] + TM - 1) / TM;
    }
    tileBase[NUM_EXPERTS] = tb;
    *totalTiles = tb;
}

// ---- fill padded row lists: LDS ranks + 8 global atomics per block ----
__global__ __launch_bounds__(512) void moe_fill_pad(
    const int* __restrict__ eidx, const float* __restrict__ ew,
    int* __restrict__ cursorP, int* __restrict__ rowTokP, float* __restrict__ rowWP)
{
    __shared__ int lh[NUM_EXPERTS], base[NUM_EXPERTS];
    if (threadIdx.x < NUM_EXPERTS) lh[threadIdx.x] = 0;
    __syncthreads();
    int i = blockIdx.x * 512 + threadIdx.x;
    int e = eidx[i];
    int rank = atomicAdd(&lh[e], 1);
    __syncthreads();
    if (threadIdx.x < NUM_EXPERTS)
        base[threadIdx.x] = atomicAdd(&cursorP[threadIdx.x], lh[threadIdx.x]);
    __syncthreads();
    int pr = base[e] + rank;
    rowTokP[pr] = i >> 1;
    rowWP[pr]   = ew[i];
}

// ---- grouped GEMM: 128x128 tile, BK=32, dbuf prefetch, direct A-gather ----
// LDS 33KB -> 4 blocks/CU (16 waves) for inter-block latency hiding (m97 regime)
__global__ __launch_bounds__(256) void moe_gemm_v4(
    const ushort_t* __restrict__ xhi, const ushort_t* __restrict__ xlo,
    const ushort_t* __restrict__ Bh, const ushort_t* __restrict__ Bl,
    const float* __restrict__ be,
    const int* __restrict__ tileBase, const int* __restrict__ totalTiles,
    const int* __restrict__ rowTokP, const float* __restrict__ rowWP,
    float* __restrict__ out)
{
    __shared__ __align__(16) ushort_t As[2][4096];   // [kg(4)][row(128)][8]
    __shared__ __align__(16) ushort_t Bs[2][4096];
    __shared__ int   tokS[TM];
    __shared__ float wS[TM];

    const int tile = blockIdx.x;
    if (tile >= *totalTiles) return;

    int e = 0;
#pragma unroll
    for (int q = 0; q < NUM_EXPERTS; ++q)
        if (tile >= tileBase[q + 1]) e = q + 1;

    const int tid  = threadIdx.x;
    const int lane = tid & 63;
    const int w    = tid >> 6;
    const int wm   = w >> 1, wn = w & 1;
    const int hw   = w & 1;                  // which half of the tile this wave stages

    if (tid < TM) {
        tokS[tid] = rowTokP[tile * TM + tid];
        wS[tid]   = rowWP[tile * TM + tid];
    }
    __syncthreads();                         // tokS visible for gather setup

    const bool stageA = (w < 2);
    int aoff[4];                             // per-lane elem offsets into x planes
    if (stageA) {
#pragma unroll
        for (int c = 0; c < 4; ++c) {
            int s   = (hw * 4 + c) * 64 + lane;
            int row = s & 127, kg = s >> 7;
            int tok = tokS[row]; if (tok < 0) tok = 0;
            aoff[c] = tok * 1024 + kg * 8;
        }
    }
    const size_t bTile = (size_t)(e * 8 + blockIdx.y) * 131072;  // 32 steps * 4096

    // stage K-step T into buffer B_: 4 x 1KB global_load_lds per wave
#define STAGE(B_, T_) do {                                                        \
        const int k0_ = ((T_) & 31) << 5;                                         \
        if (stageA) {                                                             \
            const ushort_t* p_ = (((T_) >> 5) == 1) ? xlo : xhi;                  \
            _Pragma("unroll")                                                     \
            for (int c_ = 0; c_ < 4; ++c_)                                        \
                gload_lds16(p_ + aoff[c_] + k0_, &As[B_][hw * 2048 + c_ * 512]);  \
        } else {                                                                  \
            const ushort_t* p_ = (((T_) < 64) ? Bh : Bl) + bTile                  \
                                 + (size_t)((T_) & 31) * 4096 + hw * 2048;        \
            _Pragma("unroll")                                                     \
            for (int c_ = 0; c_ < 4; ++c_)                                        \
                gload_lds16(p_ + c_ * 512 + lane * 8,                             \
                            &Bs[B_][hw * 2048 + c_ * 512]);                       \
        }                                                                         \
    } while (0)

    f32x4 acc[4][4];
#pragma unroll
    for (int m = 0; m < 4; ++m)
#pragma unroll
        for (int n = 0; n < 4; ++n) acc[m][n] = (f32x4){0.f, 0.f, 0.f, 0.f};

    const int kg = lane >> 4;
    const int rA = wm * 64 + (lane & 15);
    const int rB = wn * 64 + (lane & 15);

#define COMPUTE(B_) do {                                                          \
        short8 af[4], bf[4];                                                      \
        _Pragma("unroll")                                                         \
        for (int m_ = 0; m_ < 4; ++m_)                                            \
            af[m_] = *(const short8*)&As[B_][(kg * 128 + rA + m_ * 16) * 8];      \
        _Pragma("unroll")                                                         \
        for (int n_ = 0; n_ < 4; ++n_)                                            \
            bf[n_] = *(const short8*)&Bs[B_][(kg * 128 + rB + n_ * 16) * 8];      \
        _Pragma("unroll")                                                         \
        for (int m_ = 0; m_ < 4; ++m_)                                            \
            _Pragma("unroll")                                                     \
            for (int n_ = 0; n_ < 4; ++n_)                                        \
                acc[m_][n_] = __builtin_amdgcn_mfma_f32_16x16x32_bf16(            \
                    af[m_], bf[n_], acc[m_][n_], 0, 0, 0);                        \
    } while (0)

    STAGE(0, 0);
    __syncthreads();                 // buf0 ready
    for (int t = 0; t < NSTEP; ++t) {
        if (t + 1 < NSTEP) STAGE((t + 1) & 1, t + 1);
        COMPUTE(t & 1);
        __syncthreads();             // stage(t+1) landed; reads of buf(t) done
    }

    // epilogue: C/D layout col=lane&15, row=(lane>>4)*4+reg
    const float* bias = be + (size_t)e * D_MODEL;
    const int c0 = blockIdx.y * TN;
#pragma unroll
    for (int m = 0; m < 4; ++m) {
        int rbase = wm * 64 + m * 16 + ((lane >> 4) << 2);
#pragma unroll
        for (int n = 0; n < 4; ++n) {
            int c = c0 + wn * 64 + n * 16 + (lane & 15);
            float bv = bias[c];
            f32x4 a = acc[m][n];
#pragma unroll
            for (int r = 0; r < 4; ++r) {
                int rr = rbase + r;
                int tok = tokS[rr];
                if (tok >= 0)
                    atomicAdd(out + (size_t)tok * D_MODEL + c, wS[rr] * (a[r] + bv));
            }
        }
    }
#undef STAGE
#undef COMPUTE
}

// ---- launch ----
extern "C" void kernel_launch(void* const* d_in, const int* in_sizes, int n_in,
                              void* d_out, int out_size, void* d_ws, size_t ws_size,
                              hipStream_t stream) {
    const float* x  = (const float*)d_in[0];
    const float* We = (const float*)d_in[1];
    const float* be = (const float*)d_in[2];
    const float* Wg = (const float*)d_in[3];
    const float* bg = (const float*)d_in[4];
    float* out = (float*)d_out;

    const int N = in_sizes[0] / D_MODEL;           // 8192 tokens
    const int R = N * TOPK;                        // 16384 routed rows

    const size_t xPlane = (size_t)N * D_MODEL;                      // 8.4M elems
    const size_t wPlane = (size_t)NUM_EXPERTS * D_MODEL * D_MODEL;  // 8.4M elems

    ushort_t* xhi = (ushort_t*)d_ws;
    ushort_t* xlo = xhi + xPlane;
    ushort_t* Bh  = xlo + xPlane;
    ushort_t* Bl  = Bh + wPlane;
    int*   counts     = (int*)(Bl + wPlane);
    int*   tileBase   = counts + 8;                // 9
    int*   cursorP    = tileBase + 9;              // 8
    int*   totalTiles = cursorP + 8;               // 1
    int*   eidx       = totalTiles + 1;            // [2N]
    float* ew         = (float*)(eidx + R);        // [2N]
    int*   rowTokP    = (int*)(ew + R);            // [MAXT*128]
    float* rowWP      = (float*)(rowTokP + MAXT * TM);

    const size_t need = (size_t)((char*)(rowWP + MAXT * TM) - (char*)d_ws);
    if (ws_size < need) return;

    hipMemsetAsync(counts, 0, 32, stream);
    hipMemsetAsync(rowTokP, 0xFF, MAXT * TM * sizeof(int), stream);
    hipMemsetAsync(out, 0, (size_t)N * D_MODEL * sizeof(float), stream);

    convert_W_pack<<<2048, 256, 0, stream>>>(We, Bh, Bl);
    gate_cvt_x<<<(N + 3) / 4, 256, 0, stream>>>(x, Wg, bg, xhi, xlo, eidx, ew, N);
    moe_count<<<R / 256, 256, 0, stream>>>(eidx, counts);
    moe_scan<<<1, 1, 0, stream>>>(counts, tileBase, cursorP, totalTiles);
    moe_fill_pad<<<R / 512, 512, 0, stream>>>(eidx, ew, cursorP, rowTokP, rowWP);

    dim3 grid(MAXT, D_MODEL / TN);
    moe_gemm_v4<<<grid, 256, 0, stream>>>(xhi, xlo, Bh, Bl, be,
                                          tileBase, totalTiles, rowTokP, rowWP, out);
}

// Round 7
// 395.000 us; speedup vs baseline: 1.0546x; 1.0546x over previous
//
#include <hip/hip_runtime.h>
#include <math.h>

#define D_MODEL 1024
#define NUM_EXPERTS 8
#define TOPK 2
#define TM 128
#define TN 128
#define BK 64
#define NSTEP 48                          // 3 planes x 16 K-tiles of 64
#define MAXT (16384 / TM + NUM_EXPERTS)   // 136 padded tiles

typedef __attribute__((ext_vector_type(8))) short short8;
typedef __attribute__((ext_vector_type(4))) float f32x4;
typedef unsigned short ushort_t;

__device__ __forceinline__ unsigned short bf16_rne(float f) {
    unsigned int u = __builtin_bit_cast(unsigned int, f);
    unsigned int r = u + 0x7fffu + ((u >> 16) & 1u);
    return (unsigned short)(r >> 16);
}
__device__ __forceinline__ float bf16f(unsigned short h) {
    unsigned int u = ((unsigned int)h) << 16;
    return __builtin_bit_cast(float, u);
}
__device__ __forceinline__ void gload_lds16(const ushort_t* g, ushort_t* l) {
    __builtin_amdgcn_global_load_lds(
        (const __attribute__((address_space(1))) unsigned int*)g,
        (__attribute__((address_space(3))) unsigned int*)l, 16, 0, 0);
}
__device__ __forceinline__ void split2(float v, unsigned short& h, unsigned short& l) {
    h = bf16_rne(v); l = bf16_rne(v - bf16f(h));
}

// ---- convert We -> packed staging order [e][ct][ks32][kg][col][8], hi/lo planes ----
// (unchanged from R6; GEMM's B addressing consumes two ks32 blocks per BK=64 tile)
__global__ __launch_bounds__(256) void convert_W_pack(
    const float* __restrict__ W, ushort_t* __restrict__ hi, ushort_t* __restrict__ lo)
{
    int t = blockIdx.x * 256 + threadIdx.x;          // 524288 threads
    int k16 = t & 63, col = (t >> 6) & 127, ct = (t >> 13) & 7, e = t >> 16;
    int ks = k16 >> 1, kg0 = (k16 & 1) * 2;
    const float4* src = (const float4*)(W + ((size_t)(e * 1024 + ct * 128 + col)) * 1024
                                          + k16 * 16);
    float4 v0 = src[0], v1 = src[1], v2 = src[2], v3 = src[3];
    size_t base = (size_t)(e * 8 + ct) * 131072 + (size_t)ks * 4096;
    size_t o0 = base + (size_t)(kg0 * 128 + col) * 8;
    size_t o1 = base + (size_t)((kg0 + 1) * 128 + col) * 8;
    ushort4 h, l;
    split2(v0.x, h.x, l.x); split2(v0.y, h.y, l.y); split2(v0.z, h.z, l.z); split2(v0.w, h.w, l.w);
    ((ushort4*)(hi + o0))[0] = h; ((ushort4*)(lo + o0))[0] = l;
    split2(v1.x, h.x, l.x); split2(v1.y, h.y, l.y); split2(v1.z, h.z, l.z); split2(v1.w, h.w, l.w);
    ((ushort4*)(hi + o0))[1] = h; ((ushort4*)(lo + o0))[1] = l;
    split2(v2.x, h.x, l.x); split2(v2.y, h.y, l.y); split2(v2.z, h.z, l.z); split2(v2.w, h.w, l.w);
    ((ushort4*)(hi + o1))[0] = h; ((ushort4*)(lo + o1))[0] = l;
    split2(v3.x, h.x, l.x); split2(v3.y, h.y, l.y); split2(v3.z, h.z, l.z); split2(v3.w, h.w, l.w);
    ((ushort4*)(hi + o1))[1] = h; ((ushort4*)(lo + o1))[1] = l;
}

// ---- fused gating + x -> hi/lo bf16 planes (x read once), one wave per token ----
__global__ __launch_bounds__(256) void gate_cvt_x(
    const float* __restrict__ x, const float* __restrict__ Wg,
    const float* __restrict__ bg,
    ushort_t* __restrict__ xhi, ushort_t* __restrict__ xlo,
    int* __restrict__ eidx, float* __restrict__ ew, int N)
{
    const int wave = threadIdx.x >> 6, lane = threadIdx.x & 63;
    const int n = blockIdx.x * 4 + wave;
    if (n >= N) return;

    const float4* xr4 = (const float4*)(x + (size_t)n * D_MODEL);
    float xv[16];
#pragma unroll
    for (int j = 0; j < 4; ++j) {
        float4 v = xr4[j * 64 + lane];
        xv[4 * j + 0] = v.x; xv[4 * j + 1] = v.y;
        xv[4 * j + 2] = v.z; xv[4 * j + 3] = v.w;
        ushort4 h, l;
        split2(v.x, h.x, l.x); split2(v.y, h.y, l.y);
        split2(v.z, h.z, l.z); split2(v.w, h.w, l.w);
        ((ushort4*)(xhi + (size_t)n * D_MODEL))[j * 64 + lane] = h;
        ((ushort4*)(xlo + (size_t)n * D_MODEL))[j * 64 + lane] = l;
    }
    float logit[NUM_EXPERTS];
#pragma unroll
    for (int e = 0; e < NUM_EXPERTS; ++e) {
        const float4* wg4 = (const float4*)(Wg + (size_t)e * D_MODEL);
        float p = 0.f;
#pragma unroll
        for (int j = 0; j < 4; ++j) {
            float4 w = wg4[j * 64 + lane];
            p += xv[4 * j + 0] * w.x + xv[4 * j + 1] * w.y
               + xv[4 * j + 2] * w.z + xv[4 * j + 3] * w.w;
        }
#pragma unroll
        for (int off = 32; off >= 1; off >>= 1) p += __shfl_xor(p, off, 64);
        logit[e] = p + bg[e];
    }
    int i0 = 0; float v0 = logit[0];
#pragma unroll
    for (int e = 1; e < NUM_EXPERTS; ++e)
        if (logit[e] > v0) { v0 = logit[e]; i0 = e; }
    int i1 = -1; float v1 = -INFINITY;
#pragma unroll
    for (int e = 0; e < NUM_EXPERTS; ++e) {
        if (e == i0) continue;
        if (logit[e] > v1) { v1 = logit[e]; i1 = e; }
    }
    float e1 = expf(v1 - v0);
    float inv = 1.f / (1.f + e1);
    if (lane == 0) {
        eidx[2 * n]     = i0;
        eidx[2 * n + 1] = i1;
        ew[2 * n]       = inv;
        ew[2 * n + 1]   = e1 * inv;
    }
}

// ---- histogram: block-aggregated, 8 atomics per block ----
__global__ __launch_bounds__(256) void moe_count(
    const int* __restrict__ eidx, int* __restrict__ counts)
{
    __shared__ int h[NUM_EXPERTS];
    if (threadIdx.x < NUM_EXPERTS) h[threadIdx.x] = 0;
    __syncthreads();
    int e = eidx[blockIdx.x * 256 + threadIdx.x];
    atomicAdd(&h[e], 1);
    __syncthreads();
    if (threadIdx.x < NUM_EXPERTS) atomicAdd(&counts[threadIdx.x], h[threadIdx.x]);
}

// ---- scan ----
__global__ void moe_scan(const int* __restrict__ counts,
                         int* __restrict__ tileBase, int* __restrict__ cursorP,
                         int* __restrict__ totalTiles)
{
    int tb = 0;
    for (int e = 0; e < NUM_EXPERTS; ++e) {
        tileBase[e] = tb;
        cursorP[e]  = tb * TM;
        tb += (counts[e] + TM - 1) / TM;
    }
    tileBase[NUM_EXPERTS] = tb;
    *totalTiles = tb;
}

// ---- fill padded row lists: LDS ranks + 8 global atomics per block ----
__global__ __launch_bounds__(512) void moe_fill_pad(
    const int* __restrict__ eidx, const float* __restrict__ ew,
    int* __restrict__ cursorP, int* __restrict__ rowTokP, float* __restrict__ rowWP)
{
    __shared__ int lh[NUM_EXPERTS], base[NUM_EXPERTS];
    if (threadIdx.x < NUM_EXPERTS) lh[threadIdx.x] = 0;
    __syncthreads();
    int i = blockIdx.x * 512 + threadIdx.x;
    int e = eidx[i];
    int rank = atomicAdd(&lh[e], 1);
    __syncthreads();
    if (threadIdx.x < NUM_EXPERTS)
        base[threadIdx.x] = atomicAdd(&cursorP[threadIdx.x], lh[threadIdx.x]);
    __syncthreads();
    int pr = base[e] + rank;
    rowTokP[pr] = i >> 1;
    rowWP[pr]   = ew[i];
}

// ---- grouped GEMM v5: 128x128 tile, BK=64, dbuf, COUNTED vmcnt(8) pipeline ----
// Identical geometry to R3 (199us @ 22% MfmaUtil); only the sync structure
// changes: raw s_barrier + s_waitcnt vmcnt(8) keeps next tile's 8 loads in
// flight across the barrier instead of draining to 0 (T4 mechanism).
__global__ __launch_bounds__(256) void moe_gemm_v5(
    const ushort_t* __restrict__ xhi, const ushort_t* __restrict__ xlo,
    const ushort_t* __restrict__ Bh, const ushort_t* __restrict__ Bl,
    const float* __restrict__ be,
    const int* __restrict__ tileBase, const int* __restrict__ totalTiles,
    const int* __restrict__ rowTokP, const float* __restrict__ rowWP,
    float* __restrict__ out)
{
    __shared__ __align__(16) ushort_t As[2][8192];   // [kg8(8)][row(128)][8] = 16KB/buf
    __shared__ __align__(16) ushort_t Bs[2][8192];
    __shared__ int   tokS[TM];
    __shared__ float wS[TM];

    const int tile = blockIdx.x;
    if (tile >= *totalTiles) return;

    int e = 0;
#pragma unroll
    for (int q = 0; q < NUM_EXPERTS; ++q)
        if (tile >= tileBase[q + 1]) e = q + 1;

    const int tid  = threadIdx.x;
    const int lane = tid & 63;
    const int w    = tid >> 6;
    const int wm   = w >> 1, wn = w & 1;
    const int hw   = w & 1;                  // half of the tile this wave stages

    if (tid < TM) {
        tokS[tid] = rowTokP[tile * TM + tid];
        wS[tid]   = rowWP[tile * TM + tid];
    }
    __syncthreads();                         // tokS visible (prologue only)

    const bool stageA = (w < 2);
    // A-wave per-lane gather offsets: chunk = hw*512 + c*64 + lane
    //   row = (c&1)*64 + lane, kg8 = hw*4 + (c>>1)
    int aoff[8];
    if (stageA) {
#pragma unroll
        for (int c = 0; c < 8; ++c) {
            int row = (c & 1) * 64 + lane;
            int tok = tokS[row]; if (tok < 0) tok = 0;
            aoff[c] = tok * 1024 + (hw * 4 + (c >> 1)) * 8;
        }
    }
    const size_t bTile = (size_t)(e * 8 + blockIdx.y) * 131072;  // 32 ks32 * 4096

    // stage K-tile T (0..47) into buffer B_: 8 x 1KB global_load_lds per wave
#define STAGE(B_, T_) do {                                                        \
        const int jj_ = (T_) & 15;                                                \
        if (stageA) {                                                             \
            const ushort_t* p_ = ((((T_) >> 4) == 1) ? xlo : xhi);                \
            const int k0_ = jj_ * 64;                                             \
            _Pragma("unroll")                                                     \
            for (int c_ = 0; c_ < 8; ++c_)                                        \
                gload_lds16(p_ + aoff[c_] + k0_,                                  \
                            &As[B_][hw * 4096 + c_ * 512]);                       \
        } else {                                                                  \
            const ushort_t* p_ = (((T_) < 32) ? Bh : Bl) + bTile;                 \
            _Pragma("unroll")                                                     \
            for (int c_ = 0; c_ < 8; ++c_)                                        \
                gload_lds16(p_ + (size_t)(2 * jj_ + hw) * 4096                    \
                               + ((c_ >> 1) * 128 + (c_ & 1) * 64 + lane) * 8,    \
                            &Bs[B_][hw * 4096 + c_ * 512]);                       \
        }                                                                         \
    } while (0)

    f32x4 acc[4][4];
#pragma unroll
    for (int m = 0; m < 4; ++m)
#pragma unroll
        for (int n = 0; n < 4; ++n) acc[m][n] = (f32x4){0.f, 0.f, 0.f, 0.f};

    const int kg = lane >> 4;
    const int rA = wm * 64 + (lane & 15);
    const int rB = wn * 64 + (lane & 15);

#define COMPUTE(B_) do {                                                          \
        _Pragma("unroll")                                                         \
        for (int c_ = 0; c_ < 2; ++c_) {                                          \
            short8 af[4], bf[4];                                                  \
            _Pragma("unroll")                                                     \
            for (int m_ = 0; m_ < 4; ++m_)                                        \
                af[m_] = *(const short8*)&As[B_][((c_ * 4 + kg) * 128 + rA + m_ * 16) * 8]; \
            _Pragma("unroll")                                                     \
            for (int n_ = 0; n_ < 4; ++n_)                                        \
                bf[n_] = *(const short8*)&Bs[B_][((c_ * 4 + kg) * 128 + rB + n_ * 16) * 8]; \
            _Pragma("unroll")                                                     \
            for (int m_ = 0; m_ < 4; ++m_)                                        \
                _Pragma("unroll")                                                 \
                for (int n_ = 0; n_ < 4; ++n_)                                    \
                    acc[m_][n_] = __builtin_amdgcn_mfma_f32_16x16x32_bf16(        \
                        af[m_], bf[n_], acc[m_][n_], 0, 0, 0);                    \
        }                                                                         \
    } while (0)

    STAGE(0, 0);                         // prologue: tile 0 in flight (8 loads)
    for (int t = 0; t < NSTEP; ++t) {
        // top barrier: all waves done reading buf[(t+1)&1] (= buf[(t-1)&1])
        __builtin_amdgcn_sched_barrier(0);
        __builtin_amdgcn_s_barrier();
        __builtin_amdgcn_sched_barrier(0);
        if (t + 1 < NSTEP) {
            STAGE((t + 1) & 1, t + 1);   // +8 loads: now 16 outstanding
            __builtin_amdgcn_sched_barrier(0);
            asm volatile("s_waitcnt vmcnt(8)" ::: "memory");  // tile t landed; t+1 in flight
        } else {
            asm volatile("s_waitcnt vmcnt(0)" ::: "memory");  // tail drain
        }
        __builtin_amdgcn_s_barrier();    // all waves' vmcnt passed: buf[t&1] ready
        __builtin_amdgcn_sched_barrier(0);
        COMPUTE(t & 1);
    }

    // epilogue: C/D layout col=lane&15, row=(lane>>4)*4+reg
    const float* bias = be + (size_t)e * D_MODEL;
    const int c0 = blockIdx.y * TN;
#pragma unroll
    for (int m = 0; m < 4; ++m) {
        int rbase = wm * 64 + m * 16 + ((lane >> 4) << 2);
#pragma unroll
        for (int n = 0; n < 4; ++n) {
            int c = c0 + wn * 64 + n * 16 + (lane & 15);
            float bv = bias[c];
            f32x4 a = acc[m][n];
#pragma unroll
            for (int r = 0; r < 4; ++r) {
                int rr = rbase + r;
                int tok = tokS[rr];
                if (tok >= 0)
                    atomicAdd(out + (size_t)tok * D_MODEL + c, wS[rr] * (a[r] + bv));
            }
        }
    }
#undef STAGE
#undef COMPUTE
}

// ---- launch ----
extern "C" void kernel_launch(void* const* d_in, const int* in_sizes, int n_in,
                              void* d_out, int out_size, void* d_ws, size_t ws_size,
                              hipStream_t stream) {
    const float* x  = (const float*)d_in[0];
    const float* We = (const float*)d_in[1];
    const float* be = (const float*)d_in[2];
    const float* Wg = (const float*)d_in[3];
    const float* bg = (const float*)d_in[4];
    float* out = (float*)d_out;

    const int N = in_sizes[0] / D_MODEL;           // 8192 tokens
    const int R = N * TOPK;                        // 16384 routed rows

    const size_t xPlane = (size_t)N * D_MODEL;                      // 8.4M elems
    const size_t wPlane = (size_t)NUM_EXPERTS * D_MODEL * D_MODEL;  // 8.4M elems

    ushort_t* xhi = (ushort_t*)d_ws;
    ushort_t* xlo = xhi + xPlane;
    ushort_t* Bh  = xlo + xPlane;
    ushort_t* Bl  = Bh + wPlane;
    int*   counts     = (int*)(Bl + wPlane);
    int*   tileBase   = counts + 8;                // 9
    int*   cursorP    = tileBase + 9;              // 8
    int*   totalTiles = cursorP + 8;               // 1
    int*   eidx       = totalTiles + 1;            // [2N]
    float* ew         = (float*)(eidx + R);        // [2N]
    int*   rowTokP    = (int*)(ew + R);            // [MAXT*128]
    float* rowWP      = (float*)(rowTokP + MAXT * TM);

    const size_t need = (size_t)((char*)(rowWP + MAXT * TM) - (char*)d_ws);
    if (ws_size < need) return;

    hipMemsetAsync(counts, 0, 32, stream);
    hipMemsetAsync(rowTokP, 0xFF, MAXT * TM * sizeof(int), stream);
    hipMemsetAsync(out, 0, (size_t)N * D_MODEL * sizeof(float), stream);

    convert_W_pack<<<2048, 256, 0, stream>>>(We, Bh, Bl);
    gate_cvt_x<<<(N + 3) / 4, 256, 0, stream>>>(x, Wg, bg, xhi, xlo, eidx, ew, N);
    moe_count<<<R / 256, 256, 0, stream>>>(eidx, counts);
    moe_scan<<<1, 1, 0, stream>>>(counts, tileBase, cursorP, totalTiles);
    moe_fill_pad<<<R / 512, 512, 0, stream>>>(eidx, ew, cursorP, rowTokP, rowWP);

    dim3 grid(MAXT, D_MODEL / TN);
    moe_gemm_v5<<<grid, 256, 0, stream>>>(xhi, xlo, Bh, Bl, be,
                                          tileBase, totalTiles, rowTokP, rowWP, out);
}

// Round 8
// 378.754 us; speedup vs baseline: 1.0998x; 1.0429x over previous
//
#include <hip/hip_runtime.h>
#include <math.h>

#define D_MODEL 1024
#define NUM_EXPERTS 8
#define TOPK 2
#define TM 128
#define TN 128
#define BK 32
#define NSTEP 96                          // virtual K' = [Ahi|Alo|Ahi]x[Bhi|Bhi|Blo], 96x32
#define MAXT (16384 / TM + NUM_EXPERTS)   // 136 padded tiles

typedef __attribute__((ext_vector_type(8))) short short8;
typedef __attribute__((ext_vector_type(4))) float f32x4;
typedef unsigned short ushort_t;

__device__ __forceinline__ unsigned short bf16_rne(float f) {
    unsigned int u = __builtin_bit_cast(unsigned int, f);
    unsigned int r = u + 0x7fffu + ((u >> 16) & 1u);
    return (unsigned short)(r >> 16);
}
__device__ __forceinline__ float bf16f(unsigned short h) {
    unsigned int u = ((unsigned int)h) << 16;
    return __builtin_bit_cast(float, u);
}
__device__ __forceinline__ void gload_lds16(const ushort_t* g, ushort_t* l) {
    __builtin_amdgcn_global_load_lds(
        (const __attribute__((address_space(1))) unsigned int*)g,
        (__attribute__((address_space(3))) unsigned int*)l, 16, 0, 0);
}
__device__ __forceinline__ void split2(float v, unsigned short& h, unsigned short& l) {
    h = bf16_rne(v); l = bf16_rne(v - bf16f(h));
}

// ---- convert We -> packed staging order [e][ct][ks32][kg4][col][8], hi/lo ----
__global__ __launch_bounds__(256) void convert_W_pack(
    const float* __restrict__ W, ushort_t* __restrict__ hi, ushort_t* __restrict__ lo)
{
    int t = blockIdx.x * 256 + threadIdx.x;          // 524288 threads
    int k16 = t & 63, col = (t >> 6) & 127, ct = (t >> 13) & 7, e = t >> 16;
    int ks = k16 >> 1, kg0 = (k16 & 1) * 2;
    const float4* src = (const float4*)(W + ((size_t)(e * 1024 + ct * 128 + col)) * 1024
                                          + k16 * 16);
    float4 v0 = src[0], v1 = src[1], v2 = src[2], v3 = src[3];
    size_t base = (size_t)(e * 8 + ct) * 131072 + (size_t)ks * 4096;
    size_t o0 = base + (size_t)(kg0 * 128 + col) * 8;
    size_t o1 = base + (size_t)((kg0 + 1) * 128 + col) * 8;
    ushort4 h, l;
    split2(v0.x, h.x, l.x); split2(v0.y, h.y, l.y); split2(v0.z, h.z, l.z); split2(v0.w, h.w, l.w);
    ((ushort4*)(hi + o0))[0] = h; ((ushort4*)(lo + o0))[0] = l;
    split2(v1.x, h.x, l.x); split2(v1.y, h.y, l.y); split2(v1.z, h.z, l.z); split2(v1.w, h.w, l.w);
    ((ushort4*)(hi + o0))[1] = h; ((ushort4*)(lo + o0))[1] = l;
    split2(v2.x, h.x, l.x); split2(v2.y, h.y, l.y); split2(v2.z, h.z, l.z); split2(v2.w, h.w, l.w);
    ((ushort4*)(hi + o1))[0] = h; ((ushort4*)(lo + o1))[0] = l;
    split2(v3.x, h.x, l.x); split2(v3.y, h.y, l.y); split2(v3.z, h.z, l.z); split2(v3.w, h.w, l.w);
    ((ushort4*)(hi + o1))[1] = h; ((ushort4*)(lo + o1))[1] = l;
}

// ---- gating only (packA reads fp32 x directly), one wave per token ----
__global__ __launch_bounds__(256) void moe_gate(
    const float* __restrict__ x, const float* __restrict__ Wg,
    const float* __restrict__ bg,
    int* __restrict__ eidx, float* __restrict__ ew, int N)
{
    const int wave = threadIdx.x >> 6, lane = threadIdx.x & 63;
    const int n = blockIdx.x * 4 + wave;
    if (n >= N) return;

    const float4* xr4 = (const float4*)(x + (size_t)n * D_MODEL);
    float xv[16];
#pragma unroll
    for (int j = 0; j < 4; ++j) {
        float4 v = xr4[j * 64 + lane];
        xv[4 * j + 0] = v.x; xv[4 * j + 1] = v.y;
        xv[4 * j + 2] = v.z; xv[4 * j + 3] = v.w;
    }
    float logit[NUM_EXPERTS];
#pragma unroll
    for (int e = 0; e < NUM_EXPERTS; ++e) {
        const float4* wg4 = (const float4*)(Wg + (size_t)e * D_MODEL);
        float p = 0.f;
#pragma unroll
        for (int j = 0; j < 4; ++j) {
            float4 w = wg4[j * 64 + lane];
            p += xv[4 * j + 0] * w.x + xv[4 * j + 1] * w.y
               + xv[4 * j + 2] * w.z + xv[4 * j + 3] * w.w;
        }
#pragma unroll
        for (int off = 32; off >= 1; off >>= 1) p += __shfl_xor(p, off, 64);
        logit[e] = p + bg[e];
    }
    int i0 = 0; float v0 = logit[0];
#pragma unroll
    for (int e = 1; e < NUM_EXPERTS; ++e)
        if (logit[e] > v0) { v0 = logit[e]; i0 = e; }
    int i1 = -1; float v1 = -INFINITY;
#pragma unroll
    for (int e = 0; e < NUM_EXPERTS; ++e) {
        if (e == i0) continue;
        if (logit[e] > v1) { v1 = logit[e]; i1 = e; }
    }
    float e1 = expf(v1 - v0);
    float inv = 1.f / (1.f + e1);
    if (lane == 0) {
        eidx[2 * n]     = i0;
        eidx[2 * n + 1] = i1;
        ew[2 * n]       = inv;
        ew[2 * n + 1]   = e1 * inv;
    }
}

// ---- histogram: block-aggregated, 8 atomics per block ----
__global__ __launch_bounds__(256) void moe_count(
    const int* __restrict__ eidx, int* __restrict__ counts)
{
    __shared__ int h[NUM_EXPERTS];
    if (threadIdx.x < NUM_EXPERTS) h[threadIdx.x] = 0;
    __syncthreads();
    int e = eidx[blockIdx.x * 256 + threadIdx.x];
    atomicAdd(&h[e], 1);
    __syncthreads();
    if (threadIdx.x < NUM_EXPERTS) atomicAdd(&counts[threadIdx.x], h[threadIdx.x]);
}

// ---- scan ----
__global__ void moe_scan(const int* __restrict__ counts,
                         int* __restrict__ tileBase, int* __restrict__ cursorP,
                         int* __restrict__ totalTiles)
{
    int tb = 0;
    for (int e = 0; e < NUM_EXPERTS; ++e) {
        tileBase[e] = tb;
        cursorP[e]  = tb * TM;
        tb += (counts[e] + TM - 1) / TM;
    }
    tileBase[NUM_EXPERTS] = tb;
    *totalTiles = tb;
}

// ---- fill padded row lists: LDS ranks + 8 global atomics per block ----
__global__ __launch_bounds__(512) void moe_fill_pad(
    const int* __restrict__ eidx, const float* __restrict__ ew,
    int* __restrict__ cursorP, int* __restrict__ rowTokP, float* __restrict__ rowWP)
{
    __shared__ int lh[NUM_EXPERTS], base[NUM_EXPERTS];
    if (threadIdx.x < NUM_EXPERTS) lh[threadIdx.x] = 0;
    __syncthreads();
    int i = blockIdx.x * 512 + threadIdx.x;
    int e = eidx[i];
    int rank = atomicAdd(&lh[e], 1);
    __syncthreads();
    if (threadIdx.x < NUM_EXPERTS)
        base[threadIdx.x] = atomicAdd(&cursorP[threadIdx.x], lh[threadIdx.x]);
    __syncthreads();
    int pr = base[e] + rank;
    rowTokP[pr] = i >> 1;
    rowWP[pr]   = ew[i];
}

// ---- packA: gather+split x rows into staged order [rt][ks32][kg4][row][8] ----
// one gathered fp32 read per row per thread (64B); GEMM staging becomes linear.
__global__ __launch_bounds__(256) void moe_packA(
    const float* __restrict__ x, const int* __restrict__ rowTokP,
    const int* __restrict__ totalTiles,
    ushort_t* __restrict__ Ah, ushort_t* __restrict__ Al)
{
    int c = blockIdx.x * 256 + threadIdx.x;      // MAXT*8192 threads, 16 elems each
    int row = c & 127, kp = (c >> 7) & 1, ks = (c >> 8) & 31, rt = c >> 13;
    if (rt >= *totalTiles) return;
    int tok = rowTokP[rt * 128 + row];
    if (tok < 0) return;                         // pad rows: epilogue masks them
    const float4* src = (const float4*)(x + (size_t)tok * D_MODEL + ks * 32 + kp * 16);
    float4 v0 = src[0], v1 = src[1], v2 = src[2], v3 = src[3];
    size_t o0 = (size_t)rt * 131072 + (size_t)ks * 4096
              + (size_t)(kp * 2) * 1024 + (size_t)row * 8;   // kg = kp*2
    size_t o1 = o0 + 1024;                                   // kg = kp*2+1
    ushort4 h, l;
    split2(v0.x, h.x, l.x); split2(v0.y, h.y, l.y); split2(v0.z, h.z, l.z); split2(v0.w, h.w, l.w);
    ((ushort4*)(Ah + o0))[0] = h; ((ushort4*)(Al + o0))[0] = l;
    split2(v1.x, h.x, l.x); split2(v1.y, h.y, l.y); split2(v1.z, h.z, l.z); split2(v1.w, h.w, l.w);
    ((ushort4*)(Ah + o0))[1] = h; ((ushort4*)(Al + o0))[1] = l;
    split2(v2.x, h.x, l.x); split2(v2.y, h.y, l.y); split2(v2.z, h.z, l.z); split2(v2.w, h.w, l.w);
    ((ushort4*)(Ah + o1))[0] = h; ((ushort4*)(Al + o1))[0] = l;
    split2(v3.x, h.x, l.x); split2(v3.y, h.y, l.y); split2(v3.z, h.z, l.z); split2(v3.w, h.w, l.w);
    ((ushort4*)(Ah + o1))[1] = h; ((ushort4*)(Al + o1))[1] = l;
}

// ---- grouped GEMM v6: 128x128, BK=32, ring-4 LDS, DEPTH-3 counted vmcnt ----
// Ledger (per wave, 4 loads/tile): at iter t outstanding={t,t+1,t+2}=12;
// STAGE(t+3)->16; vmcnt(12) retires exactly tile t (in-order). Tail 8/4/0.
__global__ __launch_bounds__(256) void moe_gemm_v6(
    const ushort_t* __restrict__ Apkh, const ushort_t* __restrict__ Apkl,
    const ushort_t* __restrict__ Bh, const ushort_t* __restrict__ Bl,
    const float* __restrict__ be,
    const int* __restrict__ tileBase, const int* __restrict__ totalTiles,
    const int* __restrict__ rowTokP, const float* __restrict__ rowWP,
    float* __restrict__ out)
{
    __shared__ __align__(16) ushort_t As[4][4096];   // [kg(4)][row(128)][8] = 8KB/buf
    __shared__ __align__(16) ushort_t Bs[4][4096];
    __shared__ int   tokS[TM];
    __shared__ float wS[TM];

    const int tile = blockIdx.x;
    if (tile >= *totalTiles) return;

    int e = 0;
#pragma unroll
    for (int q = 0; q < NUM_EXPERTS; ++q)
        if (tile >= tileBase[q + 1]) e = q + 1;

    const int tid  = threadIdx.x;
    const int lane = tid & 63;
    const int w    = tid >> 6;
    const int wm   = w >> 1, wn = w & 1;
    const int hw   = w & 1;                  // half of the tile this wave stages

    if (tid < TM) {
        tokS[tid] = rowTokP[tile * TM + tid];
        wS[tid]   = rowWP[tile * TM + tid];
    }

    const bool stageA = (w < 2);
    const size_t aTile = (size_t)tile * 131072;                  // 32 ks * 4096
    const size_t bTile = (size_t)(e * 8 + blockIdx.y) * 131072;

    // stage K-tile T (0..95) into ring buffer B_: 4 x 1KB linear global_load_lds
#define STAGE(B_, T_) do {                                                        \
        const size_t ko_ = (size_t)((T_) & 31) * 4096;                            \
        const ushort_t* p_;                                                       \
        if (stageA) p_ = ((((T_) >> 5) == 1) ? Apkl : Apkh) + aTile + ko_;        \
        else        p_ = (((T_) < 64) ? Bh : Bl) + bTile + ko_;                   \
        ushort_t* d_ = (stageA ? As[B_] : Bs[B_]);                                \
        _Pragma("unroll")                                                         \
        for (int c_ = 0; c_ < 4; ++c_)                                            \
            gload_lds16(p_ + hw * 2048 + c_ * 512 + lane * 8,                     \
                        d_ + hw * 2048 + c_ * 512);                               \
    } while (0)

    f32x4 acc[4][4];
#pragma unroll
    for (int m = 0; m < 4; ++m)
#pragma unroll
        for (int n = 0; n < 4; ++n) acc[m][n] = (f32x4){0.f, 0.f, 0.f, 0.f};

    const int kg = lane >> 4;
    const int rA = wm * 64 + (lane & 15);
    const int rB = wn * 64 + (lane & 15);

#define COMPUTE(B_) do {                                                          \
        short8 af[4], bf[4];                                                      \
        _Pragma("unroll")                                                         \
        for (int m_ = 0; m_ < 4; ++m_)                                            \
            af[m_] = *(const short8*)&As[B_][(kg * 128 + rA + m_ * 16) * 8];      \
        _Pragma("unroll")                                                         \
        for (int n_ = 0; n_ < 4; ++n_)                                            \
            bf[n_] = *(const short8*)&Bs[B_][(kg * 128 + rB + n_ * 16) * 8];      \
        _Pragma("unroll")                                                         \
        for (int m_ = 0; m_ < 4; ++m_)                                            \
            _Pragma("unroll")                                                     \
            for (int n_ = 0; n_ < 4; ++n_)                                        \
                acc[m_][n_] = __builtin_amdgcn_mfma_f32_16x16x32_bf16(            \
                    af[m_], bf[n_], acc[m_][n_], 0, 0, 0);                        \
    } while (0)

    __syncthreads();                     // tokS visible (prologue)
    STAGE(0, 0); STAGE(1, 1); STAGE(2, 2);   // 12 outstanding / wave

#pragma unroll 1
    for (int t = 0; t < NSTEP; ++t) {
        __builtin_amdgcn_sched_barrier(0);   // keep compute(t-1) LDS reads above
        __builtin_amdgcn_s_barrier();        // buf (t+3)&3 (=(t-1)&3) free to overwrite
        if (t + 3 < NSTEP) STAGE((t + 3) & 3, t + 3);
        __builtin_amdgcn_sched_barrier(0);   // loads issued before the wait
        if      (t < NSTEP - 3) asm volatile("s_waitcnt vmcnt(12)" ::: "memory");
        else if (t == NSTEP - 3) asm volatile("s_waitcnt vmcnt(8)" ::: "memory");
        else if (t == NSTEP - 2) asm volatile("s_waitcnt vmcnt(4)" ::: "memory");
        else                     asm volatile("s_waitcnt vmcnt(0)" ::: "memory");
        __builtin_amdgcn_s_barrier();        // join: tile t fully in LDS
        __builtin_amdgcn_sched_barrier(0);   // ds_reads stay below the barrier
        COMPUTE(t & 3);
    }

    // epilogue: C/D layout col=lane&15, row=(lane>>4)*4+reg
    const float* bias = be + (size_t)e * D_MODEL;
    const int c0 = blockIdx.y * TN;
#pragma unroll
    for (int m = 0; m < 4; ++m) {
        int rbase = wm * 64 + m * 16 + ((lane >> 4) << 2);
#pragma unroll
        for (int n = 0; n < 4; ++n) {
            int c = c0 + wn * 64 + n * 16 + (lane & 15);
            float bv = bias[c];
            f32x4 a = acc[m][n];
#pragma unroll
            for (int r = 0; r < 4; ++r) {
                int rr = rbase + r;
                int tok = tokS[rr];
                if (tok >= 0)
                    atomicAdd(out + (size_t)tok * D_MODEL + c, wS[rr] * (a[r] + bv));
            }
        }
    }
#undef STAGE
#undef COMPUTE
}

// ---- launch ----
extern "C" void kernel_launch(void* const* d_in, const int* in_sizes, int n_in,
                              void* d_out, int out_size, void* d_ws, size_t ws_size,
                              hipStream_t stream) {
    const float* x  = (const float*)d_in[0];
    const float* We = (const float*)d_in[1];
    const float* be = (const float*)d_in[2];
    const float* Wg = (const float*)d_in[3];
    const float* bg = (const float*)d_in[4];
    float* out = (float*)d_out;

    const int N = in_sizes[0] / D_MODEL;           // 8192 tokens
    const int R = N * TOPK;                        // 16384 routed rows

    const size_t aPlane = (size_t)MAXT * 131072;                    // 17.8M elems
    const size_t wPlane = (size_t)NUM_EXPERTS * D_MODEL * D_MODEL;  // 8.4M elems

    ushort_t* Apkh = (ushort_t*)d_ws;
    ushort_t* Apkl = Apkh + aPlane;
    ushort_t* Bh   = Apkl + aPlane;
    ushort_t* Bl   = Bh + wPlane;
    int*   counts     = (int*)(Bl + wPlane);
    int*   tileBase   = counts + 8;                // 9
    int*   cursorP    = tileBase + 9;              // 8
    int*   totalTiles = cursorP + 8;               // 1
    int*   eidx       = totalTiles + 1;            // [2N]
    float* ew         = (float*)(eidx + R);        // [2N]
    int*   rowTokP    = (int*)(ew + R);            // [MAXT*128]
    float* rowWP      = (float*)(rowTokP + MAXT * TM);

    const size_t need = (size_t)((char*)(rowWP + MAXT * TM) - (char*)d_ws);
    if (ws_size < need) return;

    hipMemsetAsync(counts, 0, 32, stream);
    hipMemsetAsync(rowTokP, 0xFF, MAXT * TM * sizeof(int), stream);
    hipMemsetAsync(out, 0, (size_t)N * D_MODEL * sizeof(float), stream);

    convert_W_pack<<<2048, 256, 0, stream>>>(We, Bh, Bl);
    moe_gate<<<(N + 3) / 4, 256, 0, stream>>>(x, Wg, bg, eidx, ew, N);
    moe_count<<<R / 256, 256, 0, stream>>>(eidx, counts);
    moe_scan<<<1, 1, 0, stream>>>(counts, tileBase, cursorP, totalTiles);
    moe_fill_pad<<<R / 512, 512, 0, stream>>>(eidx, ew, cursorP, rowTokP, rowWP);
    moe_packA<<<MAXT * 8192 / 256, 256, 0, stream>>>(x, rowTokP, totalTiles, Apkh, Apkl);

    dim3 grid(MAXT, D_MODEL / TN);
    moe_gemm_v6<<<grid, 256, 0, stream>>>(Apkh, Apkl, Bh, Bl, be,
                                          tileBase, totalTiles, rowTokP, rowWP, out);
}

// Round 10
// 376.791 us; speedup vs baseline: 1.1056x; 1.0052x over previous
//
#include <hip/hip_runtime.h>
#include <math.h>

#define D_MODEL 1024
#define NUM_EXPERTS 8
#define TOPK 2
#define TM 128
#define TN 128
#define BK 64
#define KP 3072                 // virtual K' = 3 planes x 1024
#define NSTEP (KP / BK)         // 48
#define MAXT (16384 / TM + NUM_EXPERTS)   // 136 padded tiles

typedef __attribute__((ext_vector_type(8))) short short8;
typedef __attribute__((ext_vector_type(4))) float f32x4;
typedef unsigned short ushort_t;

__device__ __forceinline__ unsigned short bf16_rne(float f) {
    unsigned int u = __builtin_bit_cast(unsigned int, f);
    unsigned int r = u + 0x7fffu + ((u >> 16) & 1u);
    return (unsigned short)(r >> 16);
}
__device__ __forceinline__ float bf16f(unsigned short h) {
    unsigned int u = ((unsigned int)h) << 16;
    return __builtin_bit_cast(float, u);
}
__device__ __forceinline__ void gload_lds16(const ushort_t* g, ushort_t* l) {
    __builtin_amdgcn_global_load_lds(
        (const __attribute__((address_space(1))) unsigned int*)g,
        (__attribute__((address_space(3))) unsigned int*)l, 16, 0, 0);
}
__device__ __forceinline__ void split2(float v, unsigned short& h, unsigned short& l) {
    h = bf16_rne(v); l = bf16_rne(v - bf16f(h));
}

// ---- convert We -> staged order [e][ct][kb64][kg8][col][8], hi/lo planes ----
__global__ __launch_bounds__(256) void convert_W_sw(
    const float* __restrict__ W, ushort_t* __restrict__ hi, ushort_t* __restrict__ lo)
{
    int c = blockIdx.x * 256 + threadIdx.x;       // 1,048,576 chunks of 8 elems
    int col = c & 127, kg = (c >> 7) & 7, kb = (c >> 10) & 15;
    int ct = (c >> 14) & 7, e = c >> 17;
    const float4* src = (const float4*)(W + ((size_t)(e * 1024 + ct * 128 + col)) * 1024
                                          + kb * 64 + kg * 8);
    float4 v0 = src[0], v1 = src[1];
    ushort4 h0, l0, h1, l1;
    split2(v0.x, h0.x, l0.x); split2(v0.y, h0.y, l0.y);
    split2(v0.z, h0.z, l0.z); split2(v0.w, h0.w, l0.w);
    split2(v1.x, h1.x, l1.x); split2(v1.y, h1.y, l1.y);
    split2(v1.z, h1.z, l1.z); split2(v1.w, h1.w, l1.w);
    ((ushort4*)(hi + (size_t)c * 8))[0] = h0; ((ushort4*)(hi + (size_t)c * 8))[1] = h1;
    ((ushort4*)(lo + (size_t)c * 8))[0] = l0; ((ushort4*)(lo + (size_t)c * 8))[1] = l1;
}

// ---- gating only, one wave per token, no atomics ----
__global__ __launch_bounds__(256) void moe_gate(
    const float* __restrict__ x, const float* __restrict__ Wg,
    const float* __restrict__ bg,
    int* __restrict__ eidx, float* __restrict__ ew, int N)
{
    const int wave = threadIdx.x >> 6, lane = threadIdx.x & 63;
    const int n = blockIdx.x * 4 + wave;
    if (n >= N) return;

    const float4* xr4 = (const float4*)(x + (size_t)n * D_MODEL);
    float xv[16];
#pragma unroll
    for (int j = 0; j < 4; ++j) {
        float4 v = xr4[j * 64 + lane];
        xv[4 * j + 0] = v.x; xv[4 * j + 1] = v.y;
        xv[4 * j + 2] = v.z; xv[4 * j + 3] = v.w;
    }
    float logit[NUM_EXPERTS];
#pragma unroll
    for (int e = 0; e < NUM_EXPERTS; ++e) {
        const float4* wg4 = (const float4*)(Wg + (size_t)e * D_MODEL);
        float p = 0.f;
#pragma unroll
        for (int j = 0; j < 4; ++j) {
            float4 w = wg4[j * 64 + lane];
            p += xv[4 * j + 0] * w.x + xv[4 * j + 1] * w.y
               + xv[4 * j + 2] * w.z + xv[4 * j + 3] * w.w;
        }
#pragma unroll
        for (int off = 32; off >= 1; off >>= 1) p += __shfl_xor(p, off, 64);
        logit[e] = p + bg[e];
    }
    int i0 = 0; float v0 = logit[0];
#pragma unroll
    for (int e = 1; e < NUM_EXPERTS; ++e)
        if (logit[e] > v0) { v0 = logit[e]; i0 = e; }
    int i1 = -1; float v1 = -INFINITY;
#pragma unroll
    for (int e = 0; e < NUM_EXPERTS; ++e) {
        if (e == i0) continue;
        if (logit[e] > v1) { v1 = logit[e]; i1 = e; }
    }
    float e1 = expf(v1 - v0);
    float inv = 1.f / (1.f + e1);
    if (lane == 0) {
        eidx[2 * n]     = i0;
        eidx[2 * n + 1] = i1;
        ew[2 * n]       = inv;
        ew[2 * n + 1]   = e1 * inv;
    }
}

// ---- histogram: block-aggregated, 8 atomics per block ----
__global__ __launch_bounds__(256) void moe_count(
    const int* __restrict__ eidx, int* __restrict__ counts)
{
    __shared__ int h[NUM_EXPERTS];
    if (threadIdx.x < NUM_EXPERTS) h[threadIdx.x] = 0;
    __syncthreads();
    int e = eidx[blockIdx.x * 256 + threadIdx.x];
    atomicAdd(&h[e], 1);
    __syncthreads();
    if (threadIdx.x < NUM_EXPERTS) atomicAdd(&counts[threadIdx.x], h[threadIdx.x]);
}

// ---- scan ----
__global__ void moe_scan(const int* __restrict__ counts,
                         int* __restrict__ tileBase, int* __restrict__ cursorP,
                         int* __restrict__ totalTiles)
{
    int tb = 0;
    for (int e = 0; e < NUM_EXPERTS; ++e) {
        tileBase[e] = tb;
        cursorP[e]  = tb * TM;
        tb += (counts[e] + TM - 1) / TM;
    }
    tileBase[NUM_EXPERTS] = tb;
    *totalTiles = tb;
}

// ---- fill padded row lists: LDS ranks + 8 global atomics per block ----
__global__ __launch_bounds__(512) void moe_fill_pad(
    const int* __restrict__ eidx, const float* __restrict__ ew,
    int* __restrict__ cursorP, int* __restrict__ rowTokP, float* __restrict__ rowWP)
{
    __shared__ int lh[NUM_EXPERTS], base[NUM_EXPERTS];
    if (threadIdx.x < NUM_EXPERTS) lh[threadIdx.x] = 0;
    __syncthreads();
    int i = blockIdx.x * 512 + threadIdx.x;
    int e = eidx[i];
    int rank = atomicAdd(&lh[e], 1);
    __syncthreads();
    if (threadIdx.x < NUM_EXPERTS)
        base[threadIdx.x] = atomicAdd(&cursorP[threadIdx.x], lh[threadIdx.x]);
    __syncthreads();
    int pr = base[e] + rank;
    rowTokP[pr] = i >> 1;
    rowWP[pr]   = ew[i];
}

// ---- pack gathered A rows into staged order [rt][kb64][kg8][row][8], hi/lo ----
__global__ __launch_bounds__(256) void moe_packA(
    const float* __restrict__ x, const int* __restrict__ rowTokP,
    const int* __restrict__ totalTiles,
    ushort_t* __restrict__ Ah, ushort_t* __restrict__ Al)
{
    int c = blockIdx.x * 256 + threadIdx.x;       // MAXT*16384 chunks
    int row = c & 127, kg = (c >> 7) & 7, kb = (c >> 10) & 15, rt = c >> 14;
    if (rt >= *totalTiles) return;
    int tok = rowTokP[rt * 128 + row];
    if (tok < 0) return;                           // pad rows masked in epilogue
    const float4* src = (const float4*)(x + (size_t)tok * D_MODEL + kb * 64 + kg * 8);
    float4 v0 = src[0], v1 = src[1];
    ushort4 h0, l0, h1, l1;
    split2(v0.x, h0.x, l0.x); split2(v0.y, h0.y, l0.y);
    split2(v0.z, h0.z, l0.z); split2(v0.w, h0.w, l0.w);
    split2(v1.x, h1.x, l1.x); split2(v1.y, h1.y, l1.y);
    split2(v1.z, h1.z, l1.z); split2(v1.w, h1.w, l1.w);
    ((ushort4*)(Ah + (size_t)c * 8))[0] = h0; ((ushort4*)(Ah + (size_t)c * 8))[1] = h1;
    ((ushort4*)(Al + (size_t)c * 8))[0] = l0; ((ushort4*)(Al + (size_t)c * 8))[1] = l1;
}

// ---- grouped GEMM v7: R3 core + XCD-bijective swizzle + setprio ----
// Swizzle: F = bx + by*136 (HW round-robins F%8 across XCDs); W = (F%8)*136+F/8
// -> XCD k owns column-panel ct=k for ALL experts: per-XCD hot B panel ~0.5MB
//    (L2-resident), A/out stream once via L3. Targets measured 400MB FETCH.
__global__ __launch_bounds__(256) void moe_gemm_v7(
    const ushort_t* __restrict__ Ah, const ushort_t* __restrict__ Al,
    const ushort_t* __restrict__ Bh, const ushort_t* __restrict__ Bl,
    const float* __restrict__ be,
    const int* __restrict__ tileBase, const int* __restrict__ totalTiles,
    const int* __restrict__ rowTokP, const float* __restrict__ rowWP,
    float* __restrict__ out)
{
    __shared__ __align__(16) ushort_t As[2][8192];   // [kg8][row128][8] = 16KB/buf
    __shared__ __align__(16) ushort_t Bs[2][8192];
    __shared__ int   tokS[TM];
    __shared__ float wS[TM];

    // XCD-bijective block swizzle (1088 = 8*136 exactly)
    const int F  = blockIdx.x + blockIdx.y * MAXT;
    const int Wk = (F & 7) * MAXT + (F >> 3);
    const int tile = Wk % MAXT;        // A row-tile
    const int ct   = Wk / MAXT;        // B column-panel (0..7) — one per XCD
    if (tile >= *totalTiles) return;

    int e = 0;
#pragma unroll
    for (int q = 0; q < NUM_EXPERTS; ++q)
        if (tile >= tileBase[q + 1]) e = q + 1;

    const int tid  = threadIdx.x;
    const int lane = tid & 63;
    const int w    = tid >> 6;
    const int wm   = w >> 1, wn = w & 1;
    const int half = (w & 1) * 4096;

    if (tid < TM) {
        tokS[tid] = rowTokP[tile * TM + tid];
        wS[tid]   = rowWP[tile * TM + tid];
    }

    const size_t aTile = (size_t)tile * 131072;                  // 16 kb * 8192
    const size_t bTile = ((size_t)e * 8 + ct) * 131072;
    const bool stageA = (w < 2);
    ushort_t* dst0 = (stageA ? As[0] : Bs[0]) + half;
    ushort_t* dst1 = (stageA ? As[1] : Bs[1]) + half;

    // stage K-step t into buffer dst: 8 x 1KB linear global_load_lds
#define STAGE(DST, T) do {                                                        \
        int kb_ = (T) & 15;                                                       \
        const ushort_t* src_;                                                     \
        if (stageA) src_ = (((T) >= 16 && (T) < 32) ? Al : Ah) + aTile            \
                           + kb_ * 8192 + half;                                   \
        else        src_ = (((T) < 32) ? Bh : Bl) + bTile + kb_ * 8192 + half;    \
        _Pragma("unroll")                                                         \
        for (int i_ = 0; i_ < 8; ++i_)                                            \
            gload_lds16(src_ + i_ * 512 + lane * 8, (DST) + i_ * 512);            \
    } while (0)

    f32x4 acc[4][4];
#pragma unroll
    for (int m = 0; m < 4; ++m)
#pragma unroll
        for (int n = 0; n < 4; ++n) acc[m][n] = (f32x4){0.f, 0.f, 0.f, 0.f};

    const int kg = lane >> 4;
    const int rA = wm * 64 + (lane & 15);
    const int rB = wn * 64 + (lane & 15);

#define COMPUTE(BUF) do {                                                         \
        __builtin_amdgcn_s_setprio(1);                                            \
        _Pragma("unroll")                                                         \
        for (int c_ = 0; c_ < 2; ++c_) {                                          \
            short8 af[4], bf[4];                                                  \
            _Pragma("unroll")                                                     \
            for (int m_ = 0; m_ < 4; ++m_)                                        \
                af[m_] = *(const short8*)&As[BUF][((c_ * 4 + kg) * 128 + rA + m_ * 16) * 8]; \
            _Pragma("unroll")                                                     \
            for (int n_ = 0; n_ < 4; ++n_)                                        \
                bf[n_] = *(const short8*)&Bs[BUF][((c_ * 4 + kg) * 128 + rB + n_ * 16) * 8]; \
            _Pragma("unroll")                                                     \
            for (int m_ = 0; m_ < 4; ++m_)                                        \
                _Pragma("unroll")                                                 \
                for (int n_ = 0; n_ < 4; ++n_)                                    \
                    acc[m_][n_] = __builtin_amdgcn_mfma_f32_16x16x32_bf16(        \
                        af[m_], bf[n_], acc[m_][n_], 0, 0, 0);                    \
        }                                                                         \
        __builtin_amdgcn_s_setprio(0);                                            \
    } while (0)

    STAGE(dst0, 0);
    __syncthreads();                 // drains vmcnt(0): buf0 ready; tokS visible
    for (int t = 0; t < NSTEP; t += 2) {
        if (t + 1 < NSTEP) STAGE(dst1, t + 1);
        COMPUTE(0);
        __syncthreads();             // drains stage(t+1); reads of buf0 done
        if (t + 2 < NSTEP) STAGE(dst0, t + 2);
        COMPUTE(1);
        __syncthreads();
    }

    // epilogue: C/D layout col=lane&15, row=(lane>>4)*4+reg
    const float* bias = be + (size_t)e * D_MODEL;
    const int c0 = ct * TN;
#pragma unroll
    for (int m = 0; m < 4; ++m) {
        int rbase = wm * 64 + m * 16 + ((lane >> 4) << 2);
#pragma unroll
        for (int n = 0; n < 4; ++n) {
            int c = c0 + wn * 64 + n * 16 + (lane & 15);
            float bv = bias[c];
            f32x4 a = acc[m][n];
#pragma unroll
            for (int r = 0; r < 4; ++r) {
                int rr = rbase + r;
                int tok = tokS[rr];
                if (tok >= 0)
                    atomicAdd(out + (size_t)tok * D_MODEL + c, wS[rr] * (a[r] + bv));
            }
        }
    }
#undef STAGE
#undef COMPUTE
}

// ---- launch ----
extern "C" void kernel_launch(void* const* d_in, const int* in_sizes, int n_in,
                              void* d_out, int out_size, void* d_ws, size_t ws_size,
                              hipStream_t stream) {
    const float* x  = (const float*)d_in[0];
    const float* We = (const float*)d_in[1];
    const float* be = (const float*)d_in[2];
    const float* Wg = (const float*)d_in[3];
    const float* bg = (const float*)d_in[4];
    float* out = (float*)d_out;

    const int N = in_sizes[0] / D_MODEL;           // 8192 tokens
    const int R = N * TOPK;                        // 16384 routed rows

    const size_t aPlane = (size_t)MAXT * 131072;   // 17.8M elems
    const size_t wPlane = (size_t)NUM_EXPERTS * D_MODEL * D_MODEL;  // 8.4M elems

    ushort_t* Ah = (ushort_t*)d_ws;
    ushort_t* Al = Ah + aPlane;
    ushort_t* Bh = Al + aPlane;
    ushort_t* Bl = Bh + wPlane;
    int*   counts     = (int*)(Bl + wPlane);
    int*   tileBase   = counts + 8;                // 9
    int*   cursorP    = tileBase + 9;              // 8
    int*   totalTiles = cursorP + 8;               // 1
    int*   eidx       = totalTiles + 1;            // [2N]
    float* ew         = (float*)(eidx + R);        // [2N]
    int*   rowTokP    = (int*)(ew + R);            // [MAXT*128]
    float* rowWP      = (float*)(rowTokP + MAXT * TM);

    const size_t need = (size_t)((char*)(rowWP + MAXT * TM) - (char*)d_ws);
    if (ws_size < need) return;

    hipMemsetAsync(counts, 0, 32, stream);
    hipMemsetAsync(rowTokP, 0xFF, MAXT * TM * sizeof(int), stream);
    hipMemsetAsync(out, 0, (size_t)N * D_MODEL * sizeof(float), stream);

    convert_W_sw<<<4096, 256, 0, stream>>>(We, Bh, Bl);
    moe_gate<<<(N + 3) / 4, 256, 0, stream>>>(x, Wg, bg, eidx, ew, N);
    moe_count<<<R / 256, 256, 0, stream>>>(eidx, counts);
    moe_scan<<<1, 1, 0, stream>>>(counts, tileBase, cursorP, totalTiles);
    moe_fill_pad<<<R / 512, 512, 0, stream>>>(eidx, ew, cursorP, rowTokP, rowWP);
    moe_packA<<<MAXT * 16384 / 256, 256, 0, stream>>>(x, rowTokP, totalTiles, Ah, Al);

    dim3 grid(MAXT, D_MODEL / TN);
    moe_gemm_v7<<<grid, 256, 0, stream>>>(Ah, Al, Bh, Bl, be,
                                          tileBase, totalTiles, rowTokP, rowWP, out);
}